// Round 16
// baseline (1243.791 us; speedup 1.0000x reference)
//
#include <hip/hip_runtime.h>
#include <stdint.h>

typedef unsigned short u16;
typedef unsigned int u32;
typedef __bf16 bf16x8 __attribute__((ext_vector_type(8)));
typedef float f32x4 __attribute__((ext_vector_type(4)));
typedef float f32x16 __attribute__((ext_vector_type(16)));
typedef u16 u16x4 __attribute__((ext_vector_type(4)));
typedef u16 u16x8 __attribute__((ext_vector_type(8)));

#define MFMA16(a, b, c) __builtin_amdgcn_mfma_f32_16x16x32_bf16(a, b, c, 0, 0, 0)
#define MFMA32(a, b, c) __builtin_amdgcn_mfma_f32_32x32x16_bf16(a, b, c, 0, 0, 0)

__device__ __forceinline__ u16 f2bf(float f) {
  u32 u = __builtin_bit_cast(u32, f);
  u += 0x7FFFu + ((u >> 16) & 1u);
  return (u16)(u >> 16);
}

__device__ __forceinline__ bf16x8 ld16(const u16* p) {
  return __builtin_bit_cast(bf16x8, *(const uint4*)p);
}

__device__ __forceinline__ void gl_lds(const u16* src, u16* lds) {
  __builtin_amdgcn_global_load_lds(
      (const __attribute__((address_space(1))) u32*)src,
      (__attribute__((address_space(3))) u32*)lds, 16, 0, 0);
}

// ------- weight conversion + one-time M(f32)->Sb(bf16) state convert -------
__global__ __launch_bounds__(256) void convert_weights(
    const float* __restrict__ Wq, const float* __restrict__ Wk,
    const float* __restrict__ Wv, const float* __restrict__ fcw,
    const float* __restrict__ M, u16* __restrict__ wq_b,
    u16* __restrict__ wk_b, u16* __restrict__ wv_b, u16* __restrict__ fcw_b,
    u16* __restrict__ Sb) {
  int bx = blockIdx.x, tid = threadIdx.x;
  if (bx < 4096) {
    int i = (bx * 256 + tid) * 4;
    float4 f = *(const float4*)&fcw[i];
    u16x4 o = {f2bf(f.x), f2bf(f.y), f2bf(f.z), f2bf(f.w)};
    *(u16x4*)&fcw_b[i] = o;
  } else if (bx < 4112) {
    int i = ((bx - 4096) * 256 + tid) * 4;
    const float sc = 0.022097086912079612f;  // 1/sqrt(2048) folded into Wq
    float4 q = *(const float4*)&Wq[i];
    u16x4 oq = {f2bf(q.x * sc), f2bf(q.y * sc), f2bf(q.z * sc), f2bf(q.w * sc)};
    *(u16x4*)&wq_b[i] = oq;
    float4 k = *(const float4*)&Wk[i];
    u16x4 ok = {f2bf(k.x), f2bf(k.y), f2bf(k.z), f2bf(k.w)};
    *(u16x4*)&wk_b[i] = ok;
    float4 v = *(const float4*)&Wv[i];
    u16x4 ov = {f2bf(v.x), f2bf(v.y), f2bf(v.z), f2bf(v.w)};
    *(u16x4*)&wv_b[i] = ov;
  } else {
    size_t i = ((size_t)(bx - 4112) * 256 + tid) * 8;
    float4 f0 = *(const float4*)&M[i];
    float4 f1 = *(const float4*)&M[i + 4];
    u16x8 v = {f2bf(f0.x), f2bf(f0.y), f2bf(f0.z), f2bf(f0.w),
               f2bf(f1.x), f2bf(f1.y), f2bf(f1.z), f2bf(f1.w)};
    *(u16x8*)&Sb[i] = v;
  }
}

// ---- fused attention: in-block KV projection + Q-proj + flash attention --
// Grid 256 (1/CU), 512 threads (8 waves, 32 q-rows each; 2 q-tiles/block).
// LDS 144KB (elems): WK[128][128] @0, WV @16384, XT[64][128] @32768,
// KT[2] @40960/49152, VT[2] @57344/65536. Wq staged transiently @40960
// (KT region, dead before proj(0)). Per wave: resident Wk/Wv B-frags
// (keblk=veblk=wv>>1), tokblk=wv&1; per tile proj = 8 shared X A-frag
// reads + 16 MFMA32 + 32 ds_write_b16 (write-side XOR matches QK/PV read
// swizzles). Pipeline/tile: {QK,SM,PV}[cur] -> vmcnt(0)+bar (X(t+1)) ->
// proj(t+1)->[nxt] -> bar -> stage X(t+2). K/V never touch HBM.
__global__ __launch_bounds__(512, 1) void attn_kernel(
    const u16* __restrict__ Sb, const u16* __restrict__ wq,
    const u16* __restrict__ wk, const u16* __restrict__ wvw,
    u16* __restrict__ O, int bsh) {
  __shared__ u16 SMEM[73728];  // 144 KB
  const int WKB = 0, WVB = 16384, XTB = 32768, KTB = 40960, VTB = 57344;
  int flat = blockIdx.x;
  int xcd = flat & 7, idx = flat >> 3;
  int gl = idx & 15, qtb = idx >> 4;
  int g = xcd | (gl << 3);
  int h = g & 15, n = g >> 4;
  int tid = threadIdx.x, wv = tid >> 6, ln = tid & 63;
  int l31 = ln & 31, hh = ln >> 5;
  int q0 = qtb * 256 + wv * 32;
  int i0h = h >> 1, c0 = (h & 1) * 128;
  const u16* Xbase = Sb + (size_t)n * 4096 * 256 + c0;

  // ---- staging geometry ----
  int l16 = ln & 15, lrow4 = ln >> 4;

#define STAGE_X(kvt)                                                         \
  {                                                                          \
    _Pragma("unroll") for (int i_ = 0; i_ < 2; ++i_) {                       \
      int s_ = wv * 2 + i_;                                                  \
      int row_ = 4 * s_ + lrow4;                                             \
      int pos_ = (8 * ((kvt)*64 + row_) + i0h - bsh) & 4095;                 \
      gl_lds(&Xbase[(size_t)pos_ * 256 + ((l16 ^ (row_ & 15)) * 8)],         \
             &SMEM[XTB + s_ * 512]);                                         \
    }                                                                        \
  }

  // ---- prologue: stage Wq(@KT region), WK, WV, X(0) ----
#pragma unroll
  for (int i = 0; i < 4; ++i) {
    int s = wv * 4 + i;
    int rw = 4 * s + lrow4;
    int slot = (l16 ^ (rw & 15)) * 8;
    gl_lds(&wq[rw * 128 + slot], &SMEM[KTB + s * 512]);
    gl_lds(&wk[rw * 128 + slot], &SMEM[WKB + s * 512]);
    gl_lds(&wvw[rw * 128 + slot], &SMEM[WVB + s * 512]);
  }
  STAGE_X(0);
  __syncthreads();

  // ---- Q-projection: X rows direct from global (per-lane row jr) ----
  int jr = wv * 32 + l31;
  int posx = (8 * (qtb * 256 + jr) + i0h - bsh) & 4095;
  const u16* xrow = Xbase + (size_t)posx * 256 + hh * 8;
  bf16x8 xf[8];
#pragma unroll
  for (int cs = 0; cs < 8; ++cs) xf[cs] = ld16(&xrow[cs * 16]);
  f32x16 qd[4] = {};
#pragma unroll
  for (int cs = 0; cs < 8; ++cs) {
#pragma unroll
    for (int eb = 0; eb < 4; ++eb) {
      int er = eb * 32 + l31;
      bf16x8 wf = ld16(&SMEM[KTB + er * 128 + ((2 * cs + hh) ^ (er & 15)) * 8]);
      qd[eb] = MFMA32(wf, xf[cs], qd[eb]);
    }
  }
  bf16x8 qf[8];
#pragma unroll
  for (int kt = 0; kt < 8; ++kt) {
    const int eb = kt >> 1, r0 = 8 * (kt & 1);
    u32 wA, wB, wC, wD;
    asm("v_cvt_pk_bf16_f32 %0, %1, %2" : "=v"(wA) : "v"(qd[eb][r0 + 0]), "v"(qd[eb][r0 + 1]));
    asm("v_cvt_pk_bf16_f32 %0, %1, %2" : "=v"(wB) : "v"(qd[eb][r0 + 2]), "v"(qd[eb][r0 + 3]));
    asm("v_cvt_pk_bf16_f32 %0, %1, %2" : "=v"(wC) : "v"(qd[eb][r0 + 4]), "v"(qd[eb][r0 + 5]));
    asm("v_cvt_pk_bf16_f32 %0, %1, %2" : "=v"(wD) : "v"(qd[eb][r0 + 6]), "v"(qd[eb][r0 + 7]));
    asm("v_permlane32_swap_b32 %0, %1" : "+v"(wA), "+v"(wC));
    asm("v_permlane32_swap_b32 %0, %1" : "+v"(wB), "+v"(wD));
    uint4 ww = {wA, wB, wC, wD};
    qf[kt] = __builtin_bit_cast(bf16x8, ww);
  }

  // ---- resident Wk/Wv fragments (read once) ----
  const int keblk = wv >> 1, tokblk = wv & 1;  // veblk == keblk
  bf16x8 wkf[8], wvf[8];
  {
    int er = keblk * 32 + l31;
#pragma unroll
    for (int cs = 0; cs < 8; ++cs) {
      wkf[cs] = ld16(&SMEM[WKB + er * 128 + ((2 * cs + hh) ^ (er & 15)) * 8]);
      wvf[cs] = ld16(&SMEM[WVB + er * 128 + ((2 * cs + hh) ^ (er & 15)) * 8]);
    }
  }
  __syncthreads();  // Wq region dead; X(0) drained (prologue sync covered it)

  // ---- KV projection macro: XT -> KT[dst], VT[dst] ----
#define PROJ(dst)                                                            \
  {                                                                          \
    bf16x8 xp[8];                                                            \
    int xtok_ = tokblk * 32 + l31;                                           \
    _Pragma("unroll") for (int cs = 0; cs < 8; ++cs)                         \
        xp[cs] = ld16(&SMEM[XTB + xtok_ * 128 +                              \
                            ((2 * cs + hh) ^ (xtok_ & 15)) * 8]);            \
    f32x16 kacc = {}, vacc = {};                                             \
    _Pragma("unroll") for (int cs = 0; cs < 8; ++cs) {                       \
      kacc = MFMA32(xp[cs], wkf[cs], kacc);                                  \
      vacc = MFMA32(wvf[cs], xp[cs], vacc);                                  \
    }                                                                        \
    int ke_ = keblk * 32 + l31;                                              \
    _Pragma("unroll") for (int r = 0; r < 16; ++r) {                         \
      int tok_ = tokblk * 32 + (r & 3) + 8 * (r >> 2) + 4 * hh;              \
      SMEM[KTB + (dst)*8192 + tok_ * 128 + (((ke_ >> 3) ^ (tok_ & 15)) * 8) +\
           (ke_ & 7)] = f2bf(kacc[r]);                                       \
    }                                                                        \
    _Pragma("unroll") for (int r = 0; r < 16; ++r) {                         \
      int ev_ = keblk * 32 + (r & 3) + 8 * (r >> 2) + 4 * hh;                \
      SMEM[VTB + (dst)*8192 + ev_ * 64 + (((xtok_ >> 3) ^ (ev_ & 7)) * 8) +  \
           (xtok_ & 7)] = f2bf(vacc[r]);                                     \
    }                                                                        \
  }

  PROJ(0);
  __syncthreads();  // KT[0]/VT[0] visible; XT free
  STAGE_X(1);

  f32x16 o[4] = {};
  float m = -1e30f, l = 0.f;

#pragma unroll
  for (int t = 0; t < 8; ++t) {
    const int cur = t & 1;
    const int uKT = KTB + cur * 8192, uVT = VTB + cur * 8192;
    // QK(t)
    f32x16 s[2] = {};
#pragma unroll
    for (int kt = 0; kt < 8; ++kt) {
      int slot0 = (2 * kt + hh) ^ (l31 & 15);
      bf16x8 a0 = ld16(&SMEM[uKT + l31 * 128 + slot0 * 8]);
      s[0] = MFMA32(a0, qf[kt], s[0]);
      int row1 = 32 + l31;
      int slot1 = (2 * kt + hh) ^ (row1 & 15);
      bf16x8 a1 = ld16(&SMEM[uKT + row1 * 128 + slot1 * 8]);
      s[1] = MFMA32(a1, qf[kt], s[1]);
    }
    // online softmax
    float mx[8];
#pragma unroll
    for (int i = 0; i < 8; ++i)
      mx[i] = fmaxf(fmaxf(s[0][2 * i], s[0][2 * i + 1]),
                    fmaxf(s[1][2 * i], s[1][2 * i + 1]));
    float pm = fmaxf(fmaxf(fmaxf(mx[0], mx[1]), fmaxf(mx[2], mx[3])),
                     fmaxf(fmaxf(mx[4], mx[5]), fmaxf(mx[6], mx[7])));
    pm = fmaxf(pm, __shfl_xor(pm, 32));
    if (!__all(pm <= m + 8.f)) {
      float nm = fmaxf(m, pm);
      float al = __expf(m - nm);
      l *= al;
      m = nm;
#pragma unroll
      for (int r = 0; r < 16; ++r) {
        int qr = (r & 3) + 8 * (r >> 2) + 4 * hh;
        float av = __shfl(al, (ln & 32) | qr, 64);
        o[0][r] *= av; o[1][r] *= av; o[2][r] *= av; o[3][r] *= av;
      }
    }
#pragma unroll
    for (int kb2 = 0; kb2 < 2; ++kb2)
#pragma unroll
      for (int r = 0; r < 16; ++r) s[kb2][r] = __expf(s[kb2][r] - m);
    float sm[8];
#pragma unroll
    for (int i = 0; i < 8; ++i)
      sm[i] = (s[0][2 * i] + s[0][2 * i + 1]) + (s[1][2 * i] + s[1][2 * i + 1]);
    float rs = ((sm[0] + sm[1]) + (sm[2] + sm[3])) +
               ((sm[4] + sm[5]) + (sm[6] + sm[7]));
    rs += __shfl_xor(rs, 32);
    l += rs;
    // P -> A-frags in-register (T12)
    bf16x8 pa[4];
#pragma unroll
    for (int ks = 0; ks < 4; ++ks) {
      const int kb2 = ks >> 1, r0 = 8 * (ks & 1);
      u32 wA, wB, wC, wD;
      asm("v_cvt_pk_bf16_f32 %0, %1, %2" : "=v"(wA) : "v"(s[kb2][r0 + 0]), "v"(s[kb2][r0 + 1]));
      asm("v_cvt_pk_bf16_f32 %0, %1, %2" : "=v"(wB) : "v"(s[kb2][r0 + 2]), "v"(s[kb2][r0 + 3]));
      asm("v_cvt_pk_bf16_f32 %0, %1, %2" : "=v"(wC) : "v"(s[kb2][r0 + 4]), "v"(s[kb2][r0 + 5]));
      asm("v_cvt_pk_bf16_f32 %0, %1, %2" : "=v"(wD) : "v"(s[kb2][r0 + 6]), "v"(s[kb2][r0 + 7]));
      asm("v_permlane32_swap_b32 %0, %1" : "+v"(wA), "+v"(wC));
      asm("v_permlane32_swap_b32 %0, %1" : "+v"(wB), "+v"(wD));
      uint4 ww = {wA, wB, wC, wD};
      pa[ks] = __builtin_bit_cast(bf16x8, ww);
    }
    // PV(t)
    __builtin_amdgcn_s_setprio(1);
#pragma unroll
    for (int ks = 0; ks < 4; ++ks)
#pragma unroll
      for (int nb = 0; nb < 4; ++nb) {
        int row = nb * 32 + l31;
        int slot = (2 * ks + hh) ^ (row & 7);
        bf16x8 bv = ld16(&SMEM[uVT + row * 64 + slot * 8]);
        o[nb] = MFMA32(pa[ks], bv, o[nb]);
      }
    __builtin_amdgcn_s_setprio(0);
    if (t < 7) {
      asm volatile("s_waitcnt vmcnt(0)" ::: "memory");  // X(t+1) landed
      __builtin_amdgcn_s_barrier();
      PROJ((t + 1) & 1);
      __builtin_amdgcn_s_barrier();  // proj visible; XT free
      if (t < 6) STAGE_X(t + 2);
    }
  }
#undef PROJ
#undef STAGE_X

  float inv = 1.f / l;
#pragma unroll
  for (int r = 0; r < 16; ++r) {
    int qr = (r & 3) + 8 * (r >> 2) + 4 * hh;
    float iv = __shfl(inv, (ln & 32) | qr, 64);
    int row = q0 + qr;
    u16* dst = O + ((size_t)n * 512 + row) * 2048 + h * 128;
    dst[0 * 32 + l31] = f2bf(o[0][r] * iv);
    dst[1 * 32 + l31] = f2bf(o[1][r] * iv);
    dst[2 * 32 + l31] = f2bf(o[2][r] * iv);
    dst[3 * 32 + l31] = f2bf(o[3][r] * iv);
  }
}

// ---------------- FC GEMM (R9/R13 structure, MFMA16, known-good) ----------
__global__ __launch_bounds__(512, 1) void fc_kernel(
    const u16* __restrict__ A, const u16* __restrict__ Bw,
    const float* __restrict__ bias, float* __restrict__ doutF,
    u16* __restrict__ doutB, int last, int bsh) {
  __shared__ u16 AL[3][256 * 64];
  __shared__ u16 BL[3][128 * 64];
  int blk = blockIdx.x;
  int xcd = blk & 7, j = blk >> 3;
  int bn = xcd * 2 + (j & 1), bm = j >> 1;
  int tid = threadIdx.x, wv = tid >> 6, ln = tid & 63;
  int lr = ln & 15, lg = ln >> 4;
  int R0 = bm * 256, C0 = bn * 128;
  int wr = (wv >> 1) * 64, wc = (wv & 1) * 64;
  const u16* gA[4];
  int sA[4];
  const u16* gB[2];
  int sB[2];
#pragma unroll
  for (int i = 0; i < 4; ++i) {
    int r = wv * 32 + i * 8 + (ln >> 3);
    int cs = ((ln & 7) ^ (r & 7)) * 8;
    gA[i] = A + (size_t)(R0 + r) * 2048 + cs;
    sA[i] = (wv * 32 + i * 8) * 64;
  }
#pragma unroll
  for (int i = 0; i < 2; ++i) {
    int r = wv * 16 + i * 8 + (ln >> 3);
    int cs = ((ln & 7) ^ (r & 7)) * 8;
    gB[i] = Bw + (size_t)(C0 + r) * 2048 + cs;
    sB[i] = (wv * 16 + i * 8) * 64;
  }
  int aoff[4][2], boff[4][2];
#pragma unroll
  for (int i = 0; i < 4; ++i) {
    int ra = wr + i * 16 + lr, rb = wc + i * 16 + lr;
#pragma unroll
    for (int kk = 0; kk < 2; ++kk) {
      aoff[i][kk] = ra * 64 + (((kk * 4 + lg) ^ (ra & 7)) * 8);
      boff[i][kk] = rb * 64 + (((kk * 4 + lg) ^ (rb & 7)) * 8);
    }
  }
  f32x4 acc[4][4] = {};

#define STAGE6(buf, k0)                          \
  {                                              \
    gl_lds(gA[0] + (k0), &AL[buf][sA[0]]);       \
    gl_lds(gA[1] + (k0), &AL[buf][sA[1]]);       \
    gl_lds(gA[2] + (k0), &AL[buf][sA[2]]);       \
    gl_lds(gA[3] + (k0), &AL[buf][sA[3]]);       \
    gl_lds(gB[0] + (k0), &BL[buf][sB[0]]);       \
    gl_lds(gB[1] + (k0), &BL[buf][sB[1]]);       \
  }

  STAGE6(0, 0);
  STAGE6(1, 64);
  asm volatile("s_waitcnt vmcnt(6)" ::: "memory");
  __builtin_amdgcn_s_barrier();

  for (int t = 0; t < 32; ++t) {
    int cur = t % 3, nx2 = (t + 2) % 3;
    int k2 = (t + 2) * 64;
    bf16x8 a0 = ld16(&AL[cur][aoff[0][0]]), a1 = ld16(&AL[cur][aoff[1][0]]);
    bf16x8 a2 = ld16(&AL[cur][aoff[2][0]]), a3 = ld16(&AL[cur][aoff[3][0]]);
    bf16x8 b0 = ld16(&BL[cur][boff[0][0]]), b1 = ld16(&BL[cur][boff[1][0]]);
    bf16x8 b2 = ld16(&BL[cur][boff[2][0]]), b3 = ld16(&BL[cur][boff[3][0]]);
    if (t < 30) {
      gl_lds(gA[0] + k2, &AL[nx2][sA[0]]);
      gl_lds(gA[1] + k2, &AL[nx2][sA[1]]);
      gl_lds(gB[0] + k2, &BL[nx2][sB[0]]);
    }
    __builtin_amdgcn_s_barrier();
    asm volatile("s_waitcnt lgkmcnt(0)" ::: "memory");
    __builtin_amdgcn_sched_barrier(0);
    __builtin_amdgcn_s_setprio(1);
    acc[0][0] = MFMA16(a0, b0, acc[0][0]);
    acc[0][1] = MFMA16(a0, b1, acc[0][1]);
    acc[0][2] = MFMA16(a0, b2, acc[0][2]);
    acc[0][3] = MFMA16(a0, b3, acc[0][3]);
    acc[1][0] = MFMA16(a1, b0, acc[1][0]);
    acc[1][1] = MFMA16(a1, b1, acc[1][1]);
    acc[1][2] = MFMA16(a1, b2, acc[1][2]);
    acc[1][3] = MFMA16(a1, b3, acc[1][3]);
    acc[2][0] = MFMA16(a2, b0, acc[2][0]);
    acc[2][1] = MFMA16(a2, b1, acc[2][1]);
    acc[2][2] = MFMA16(a2, b2, acc[2][2]);
    acc[2][3] = MFMA16(a2, b3, acc[2][3]);
    acc[3][0] = MFMA16(a3, b0, acc[3][0]);
    acc[3][1] = MFMA16(a3, b1, acc[3][1]);
    acc[3][2] = MFMA16(a3, b2, acc[3][2]);
    acc[3][3] = MFMA16(a3, b3, acc[3][3]);
    __builtin_amdgcn_s_setprio(0);
    __builtin_amdgcn_s_barrier();
    a0 = ld16(&AL[cur][aoff[0][1]]); a1 = ld16(&AL[cur][aoff[1][1]]);
    a2 = ld16(&AL[cur][aoff[2][1]]); a3 = ld16(&AL[cur][aoff[3][1]]);
    b0 = ld16(&BL[cur][boff[0][1]]); b1 = ld16(&BL[cur][boff[1][1]]);
    b2 = ld16(&BL[cur][boff[2][1]]); b3 = ld16(&BL[cur][boff[3][1]]);
    if (t < 30) {
      gl_lds(gA[2] + k2, &AL[nx2][sA[2]]);
      gl_lds(gA[3] + k2, &AL[nx2][sA[3]]);
      gl_lds(gB[1] + k2, &BL[nx2][sB[1]]);
      asm volatile("s_waitcnt vmcnt(6)" ::: "memory");
    } else if (t == 30) {
      asm volatile("s_waitcnt vmcnt(0)" ::: "memory");
    }
    __builtin_amdgcn_s_barrier();
    asm volatile("s_waitcnt lgkmcnt(0)" ::: "memory");
    __builtin_amdgcn_sched_barrier(0);
    __builtin_amdgcn_s_setprio(1);
    acc[0][0] = MFMA16(a0, b0, acc[0][0]);
    acc[0][1] = MFMA16(a0, b1, acc[0][1]);
    acc[0][2] = MFMA16(a0, b2, acc[0][2]);
    acc[0][3] = MFMA16(a0, b3, acc[0][3]);
    acc[1][0] = MFMA16(a1, b0, acc[1][0]);
    acc[1][1] = MFMA16(a1, b1, acc[1][1]);
    acc[1][2] = MFMA16(a1, b2, acc[1][2]);
    acc[1][3] = MFMA16(a1, b3, acc[1][3]);
    acc[2][0] = MFMA16(a2, b0, acc[2][0]);
    acc[2][1] = MFMA16(a2, b1, acc[2][1]);
    acc[2][2] = MFMA16(a2, b2, acc[2][2]);
    acc[2][3] = MFMA16(a2, b3, acc[2][3]);
    acc[3][0] = MFMA16(a3, b0, acc[3][0]);
    acc[3][1] = MFMA16(a3, b1, acc[3][1]);
    acc[3][2] = MFMA16(a3, b2, acc[3][2]);
    acc[3][3] = MFMA16(a3, b3, acc[3][3]);
    __builtin_amdgcn_s_setprio(0);
    __builtin_amdgcn_s_barrier();
  }
#undef STAGE6
#pragma unroll
  for (int nc = 0; nc < 4; ++nc) {
    int e = C0 + wc + nc * 16 + lr;
    float bv = bias[e];
    int i = e >> 8, cc = e & 255;
#pragma unroll
    for (int mt = 0; mt < 4; ++mt)
#pragma unroll
      for (int r = 0; r < 4; ++r) {
        int row = R0 + wr + mt * 16 + lg * 4 + r;
        int nn = row >> 9, jj = row & 511;
        int pos = (8 * jj + i - bsh) & 4095;
        size_t di = ((size_t)nn * 4096 + pos) * 256 + cc;
        float v = acc[mt][nc][r] + bv;
        if (last) doutF[di] = v;
        else doutB[di] = f2bf(v);
      }
  }
}

extern "C" void kernel_launch(void* const* d_in, const int* in_sizes, int n_in,
                              void* d_out, int out_size, void* d_ws, size_t ws_size,
                              hipStream_t stream) {
  const float* M = (const float*)d_in[0];
  const float* Wq = (const float*)d_in[1];
  const float* Wk = (const float*)d_in[2];
  const float* Wv = (const float*)d_in[3];
  const float* fcw = (const float*)d_in[4];
  const float* fcb = (const float*)d_in[5];
  float* out = (float*)d_out;
  char* ws = (char*)d_ws;
  u16* wq_b = (u16*)(ws + (0 << 10));
  u16* wk_b = (u16*)(ws + (32 << 10));
  u16* wv_b = (u16*)(ws + (64 << 10));
  u16* fcw_b = (u16*)(ws + (128 << 10));
  u16* Ab = (u16*)(ws + ((size_t)64 << 20));
  u16* Sb = (u16*)(ws + ((size_t)96 << 20));  // bf16 state (16.8 MB)

  convert_weights<<<8208, 256, 0, stream>>>(Wq, Wk, Wv, fcw, M, wq_b, wk_b,
                                            wv_b, fcw_b, Sb);
  for (int b = 0; b < 8; ++b) {
    attn_kernel<<<256, 512, 0, stream>>>(Sb, wq_b, wk_b, wv_b, Ab, b);
    fc_kernel<<<256, 512, 0, stream>>>(Ab, fcw_b, fcb, out, Sb,
                                       (b == 7) ? 1 : 0, b);
  }
}

// Round 17
// 664.562 us; speedup vs baseline: 1.8716x; 1.8716x over previous
//
#include <hip/hip_runtime.h>
#include <stdint.h>

typedef unsigned short u16;
typedef unsigned int u32;
typedef __bf16 bf16x8 __attribute__((ext_vector_type(8)));
typedef float f32x4 __attribute__((ext_vector_type(4)));
typedef float f32x16 __attribute__((ext_vector_type(16)));
typedef u16 u16x4 __attribute__((ext_vector_type(4)));
typedef u16 u16x8 __attribute__((ext_vector_type(8)));

#define MFMA16(a, b, c) __builtin_amdgcn_mfma_f32_16x16x32_bf16(a, b, c, 0, 0, 0)
#define MFMA32(a, b, c) __builtin_amdgcn_mfma_f32_32x32x16_bf16(a, b, c, 0, 0, 0)

__device__ __forceinline__ u16 f2bf(float f) {
  u32 u = __builtin_bit_cast(u32, f);
  u += 0x7FFFu + ((u >> 16) & 1u);
  return (u16)(u >> 16);
}

__device__ __forceinline__ bf16x8 ld16(const u16* p) {
  return __builtin_bit_cast(bf16x8, *(const uint4*)p);
}

__device__ __forceinline__ void gl_lds(const u16* src, u16* lds) {
  __builtin_amdgcn_global_load_lds(
      (const __attribute__((address_space(1))) u32*)src,
      (__attribute__((address_space(3))) u32*)lds, 16, 0, 0);
}

// ------- weight conversion + one-time M(f32)->Sb(bf16) state convert -------
__global__ __launch_bounds__(256) void convert_weights(
    const float* __restrict__ Wq, const float* __restrict__ Wk,
    const float* __restrict__ Wv, const float* __restrict__ fcw,
    const float* __restrict__ M, u16* __restrict__ wq_b,
    u16* __restrict__ wk_b, u16* __restrict__ wv_b, u16* __restrict__ fcw_b,
    u16* __restrict__ Sb) {
  int bx = blockIdx.x, tid = threadIdx.x;
  if (bx < 4096) {
    int i = (bx * 256 + tid) * 4;
    float4 f = *(const float4*)&fcw[i];
    u16x4 o = {f2bf(f.x), f2bf(f.y), f2bf(f.z), f2bf(f.w)};
    *(u16x4*)&fcw_b[i] = o;
  } else if (bx < 4112) {
    int i = ((bx - 4096) * 256 + tid) * 4;
    const float sc = 0.022097086912079612f;  // 1/sqrt(2048) folded into Wq
    float4 q = *(const float4*)&Wq[i];
    u16x4 oq = {f2bf(q.x * sc), f2bf(q.y * sc), f2bf(q.z * sc), f2bf(q.w * sc)};
    *(u16x4*)&wq_b[i] = oq;
    float4 k = *(const float4*)&Wk[i];
    u16x4 ok = {f2bf(k.x), f2bf(k.y), f2bf(k.z), f2bf(k.w)};
    *(u16x4*)&wk_b[i] = ok;
    float4 v = *(const float4*)&Wv[i];
    u16x4 ov = {f2bf(v.x), f2bf(v.y), f2bf(v.z), f2bf(v.w)};
    *(u16x4*)&wv_b[i] = ov;
  } else {
    size_t i = ((size_t)(bx - 4112) * 256 + tid) * 8;
    float4 f0 = *(const float4*)&M[i];
    float4 f1 = *(const float4*)&M[i + 4];
    u16x8 v = {f2bf(f0.x), f2bf(f0.y), f2bf(f0.z), f2bf(f0.w),
               f2bf(f1.x), f2bf(f1.y), f2bf(f1.z), f2bf(f1.w)};
    *(u16x8*)&Sb[i] = v;
  }
}

// ---------------- KV projection, 2 heads per block ----------------
__global__ __launch_bounds__(512) void kv_kernel(
    const u16* __restrict__ srcB, const u16* __restrict__ wk,
    const u16* __restrict__ wvw, u16* __restrict__ K, u16* __restrict__ Vt,
    int bsh) {
  __shared__ u16 X[64 * 264];
  int jt = blockIdx.x, i0 = blockIdx.y, n = blockIdx.z;
  int tid = threadIdx.x;
#pragma unroll
  for (int it = 0; it < 4; ++it) {
    int c = tid + it * 512;
    int row = c >> 5, seg = c & 31;
    int pos = (8 * (jt * 64 + row) + i0 - bsh) & 4095;
    size_t base = ((size_t)n * 4096 + pos) * 256 + seg * 8;
    *(u16x8*)&X[row * 264 + seg * 8] = *(const u16x8*)&srcB[base];
  }
  __syncthreads();
  int wvid = tid >> 6, ln = tid & 63;
  int mat = wvid >> 2, hc = wvid & 3;
  int hh = hc >> 1, cb = (hc & 1) * 64;
  int h = i0 * 2 + hh, xc = hh * 128;
  const u16* W = (mat == 0) ? wk : wvw;
  int lr = ln & 15, lg = ln >> 4;
  f32x4 acc[4][4] = {};
#pragma unroll
  for (int kt = 0; kt < 4; ++kt) {
    bf16x8 a[4], b[4];
#pragma unroll
    for (int mt = 0; mt < 4; ++mt)
      a[mt] = ld16(&X[(mt * 16 + lr) * 264 + xc + kt * 32 + lg * 8]);
#pragma unroll
    for (int nc = 0; nc < 4; ++nc)
      b[nc] = ld16(&W[(cb + nc * 16 + lr) * 128 + kt * 32 + lg * 8]);
#pragma unroll
    for (int mt = 0; mt < 4; ++mt)
#pragma unroll
      for (int nc = 0; nc < 4; ++nc)
        acc[mt][nc] = MFMA16(a[mt], b[nc], acc[mt][nc]);
  }
  size_t nh = (size_t)(n * 16 + h);
  if (mat == 0) {
    u16* dst = K + nh * 512 * 128;
#pragma unroll
    for (int mt = 0; mt < 4; ++mt)
#pragma unroll
      for (int nc = 0; nc < 4; ++nc) {
        int col = cb + nc * 16 + lr;
        int jb = jt * 64 + mt * 16 + lg * 4;
#pragma unroll
        for (int r = 0; r < 4; ++r)
          dst[(size_t)(jb + r) * 128 + col] = f2bf(acc[mt][nc][r]);
      }
  } else {
    u16* dst = Vt + nh * 128 * 512;
#pragma unroll
    for (int mt = 0; mt < 4; ++mt)
#pragma unroll
      for (int nc = 0; nc < 4; ++nc) {
        int col = cb + nc * 16 + lr;
        int jb = jt * 64 + mt * 16 + lg * 4;
        u16x4 pk = {f2bf(acc[mt][nc][0]), f2bf(acc[mt][nc][1]),
                    f2bf(acc[mt][nc][2]), f2bf(acc[mt][nc][3])};
        *(u16x4*)&dst[(size_t)col * 512 + jb] = pk;
      }
  }
}

// ---- flash attention: 2 q-tiles/block, X-from-global Q-proj -------------
// Grid 256 (1/CU), 512 threads (8 waves, 32 q-rows each).
__global__ __launch_bounds__(512, 1) void attn_kernel(
    const u16* __restrict__ Sb, const u16* __restrict__ wq,
    const u16* __restrict__ K, const u16* __restrict__ Vt,
    u16* __restrict__ O, int bsh) {
  __shared__ u16 SMEM[40960];  // 80 KB
#define KLp(b) (&SMEM[(b) * 8192])
#define VLp(b) (&SMEM[24576 + (b) * 8192])
#define WQB 8192  // Wq staged @8192..24575 (KL[1]+KL[2]), dead after Q-proj
  int flat = blockIdx.x;
  int xcd = flat & 7, idx = flat >> 3;
  int gl = idx & 15, qtb = idx >> 4;
  int g = xcd | (gl << 3);
  int h = g & 15, n = g >> 4;
  int tid = threadIdx.x, wv = tid >> 6, ln = tid & 63;
  int l31 = ln & 31, hh = ln >> 5;
  size_t nh = (size_t)(n * 16 + h);
  int q0 = qtb * 256 + wv * 32;
  const u16* Kb = K + (size_t)nh * 512 * 128;
  const u16* Vb = Vt + (size_t)nh * 128 * 512;
  int i0h = h >> 1, c0 = (h & 1) * 128;

  // per-wave K/V staging geometry (2 instrs each; source-side XOR swizzle)
  int rK[2], cK[2], rV[2], cV[2];
#pragma unroll
  for (int i = 0; i < 2; ++i) {
    int s = wv * 2 + i;
    rK[i] = 4 * s + (ln >> 4);
    cK[i] = ((ln & 15) ^ (rK[i] & 15)) * 8;
    rV[i] = 8 * s + (ln >> 3);
    cV[i] = ((ln & 7) ^ (rV[i] & 7)) * 8;
  }

#define STAGE_K(buf, kv)                                                     \
  {                                                                          \
    const u16* kp_ = Kb + (size_t)(kv) * 64 * 128;                           \
    _Pragma("unroll") for (int i_ = 0; i_ < 2; ++i_) {                       \
      int s_ = wv * 2 + i_;                                                  \
      gl_lds(&kp_[(size_t)rK[i_] * 128 + cK[i_]], &KLp(buf)[s_ * 512]);      \
    }                                                                        \
  }
#define STAGE_V(buf, kv)                                                     \
  {                                                                          \
    _Pragma("unroll") for (int i_ = 0; i_ < 2; ++i_) {                       \
      int s_ = wv * 2 + i_;                                                  \
      gl_lds(&Vb[(size_t)rV[i_] * 512 + (kv)*64 + cV[i_]], &VLp(buf)[s_ * 512]); \
    }                                                                        \
  }

  // ---- prologue: stage Wq (whole, 4 instrs/thread) + K(0) + V(0) ----
#pragma unroll
  for (int i = 0; i < 4; ++i) {
    int s = wv * 4 + i;                  // 0..31
    int rw = 4 * s + (ln >> 4);          // 0..127
    int slot = (ln & 15) ^ (rw & 15);
    gl_lds(&wq[rw * 128 + slot * 8], &SMEM[WQB + s * 512]);
  }
  STAGE_K(0, 0);
  STAGE_V(1, 0);  // V(0) -> VL[1]
  __syncthreads();

  // ---- Q-projection: X rows read direct from global (per-lane row jr) ----
  int jr = wv * 32 + l31;
  int posx = (8 * (qtb * 256 + jr) + i0h - bsh) & 4095;
  const u16* xrow = Sb + ((size_t)n * 4096 + posx) * 256 + c0 + hh * 8;
  bf16x8 xf[8];
#pragma unroll
  for (int cs = 0; cs < 8; ++cs) xf[cs] = ld16(&xrow[cs * 16]);
  f32x16 qd[4] = {};
#pragma unroll
  for (int cs = 0; cs < 8; ++cs) {
#pragma unroll
    for (int eb = 0; eb < 4; ++eb) {
      int er = eb * 32 + l31;
      bf16x8 wf = ld16(&SMEM[WQB + er * 128 + ((2 * cs + hh) ^ (er & 15)) * 8]);
      qd[eb] = MFMA32(wf, xf[cs], qd[eb]);
    }
  }
  // ---- relayout qd -> qf (B-frag: lane holds Q[j=l31][kt*16+hh*8+0..7]) ----
  bf16x8 qf[8];
#pragma unroll
  for (int kt = 0; kt < 8; ++kt) {
    const int eb = kt >> 1, r0 = 8 * (kt & 1);
    u32 wA, wB, wC, wD;
    asm("v_cvt_pk_bf16_f32 %0, %1, %2" : "=v"(wA) : "v"(qd[eb][r0 + 0]), "v"(qd[eb][r0 + 1]));
    asm("v_cvt_pk_bf16_f32 %0, %1, %2" : "=v"(wB) : "v"(qd[eb][r0 + 2]), "v"(qd[eb][r0 + 3]));
    asm("v_cvt_pk_bf16_f32 %0, %1, %2" : "=v"(wC) : "v"(qd[eb][r0 + 4]), "v"(qd[eb][r0 + 5]));
    asm("v_cvt_pk_bf16_f32 %0, %1, %2" : "=v"(wD) : "v"(qd[eb][r0 + 6]), "v"(qd[eb][r0 + 7]));
    asm("v_permlane32_swap_b32 %0, %1" : "+v"(wA), "+v"(wC));
    asm("v_permlane32_swap_b32 %0, %1" : "+v"(wB), "+v"(wD));
    uint4 ww = {wA, wB, wC, wD};
    qf[kt] = __builtin_bit_cast(bf16x8, ww);
  }
  __syncthreads();  // Wq region (KL[1],KL[2]) dead; all waves done

  STAGE_K(1, 1);  // 2 loads, left in flight entering the loop (steady state)

  f32x16 o[4] = {};
  float m = -1e30f, l = 0.f;

#pragma unroll
  for (int t = 0; t < 8; ++t) {
    // stage V(t+1) FIRST, then K(t+2) (rides across this tile's barrier)
    if (t < 7) STAGE_V(t & 1, t + 1);
    if (t < 6) STAGE_K((t + 2) % 3, t + 2);
    // QK(t) from KL[t%3]
    f32x16 s[2] = {};
#pragma unroll
    for (int kt = 0; kt < 8; ++kt) {
      int slot0 = (2 * kt + hh) ^ (l31 & 15);
      bf16x8 a0 = ld16(&KLp(t % 3)[l31 * 128 + slot0 * 8]);
      s[0] = MFMA32(a0, qf[kt], s[0]);
      int row1 = 32 + l31;
      int slot1 = (2 * kt + hh) ^ (row1 & 15);
      bf16x8 a1 = ld16(&KLp(t % 3)[row1 * 128 + slot1 * 8]);
      s[1] = MFMA32(a1, qf[kt], s[1]);
    }
    // online softmax
    float mx[8];
#pragma unroll
    for (int i = 0; i < 8; ++i)
      mx[i] = fmaxf(fmaxf(s[0][2 * i], s[0][2 * i + 1]),
                    fmaxf(s[1][2 * i], s[1][2 * i + 1]));
    float pm = fmaxf(fmaxf(fmaxf(mx[0], mx[1]), fmaxf(mx[2], mx[3])),
                     fmaxf(fmaxf(mx[4], mx[5]), fmaxf(mx[6], mx[7])));
    pm = fmaxf(pm, __shfl_xor(pm, 32));
    if (!__all(pm <= m + 8.f)) {
      float nm = fmaxf(m, pm);
      float al = __expf(m - nm);
      l *= al;
      m = nm;
#pragma unroll
      for (int r = 0; r < 16; ++r) {
        int qr = (r & 3) + 8 * (r >> 2) + 4 * hh;
        float av = __shfl(al, (ln & 32) | qr, 64);
        o[0][r] *= av; o[1][r] *= av; o[2][r] *= av; o[3][r] *= av;
      }
    }
#pragma unroll
    for (int kb2 = 0; kb2 < 2; ++kb2)
#pragma unroll
      for (int r = 0; r < 16; ++r) s[kb2][r] = __expf(s[kb2][r] - m);
    float sm[8];
#pragma unroll
    for (int i = 0; i < 8; ++i)
      sm[i] = (s[0][2 * i] + s[0][2 * i + 1]) + (s[1][2 * i] + s[1][2 * i + 1]);
    float rs = ((sm[0] + sm[1]) + (sm[2] + sm[3])) +
               ((sm[4] + sm[5]) + (sm[6] + sm[7]));
    rs += __shfl_xor(rs, 32);
    l += rs;
    // P -> A-frags in-register (T12)
    bf16x8 pa[4];
#pragma unroll
    for (int ks = 0; ks < 4; ++ks) {
      const int kb2 = ks >> 1, r0 = 8 * (ks & 1);
      u32 wA, wB, wC, wD;
      asm("v_cvt_pk_bf16_f32 %0, %1, %2" : "=v"(wA) : "v"(s[kb2][r0 + 0]), "v"(s[kb2][r0 + 1]));
      asm("v_cvt_pk_bf16_f32 %0, %1, %2" : "=v"(wB) : "v"(s[kb2][r0 + 2]), "v"(s[kb2][r0 + 3]));
      asm("v_cvt_pk_bf16_f32 %0, %1, %2" : "=v"(wC) : "v"(s[kb2][r0 + 4]), "v"(s[kb2][r0 + 5]));
      asm("v_cvt_pk_bf16_f32 %0, %1, %2" : "=v"(wD) : "v"(s[kb2][r0 + 6]), "v"(s[kb2][r0 + 7]));
      asm("v_permlane32_swap_b32 %0, %1" : "+v"(wA), "+v"(wC));
      asm("v_permlane32_swap_b32 %0, %1" : "+v"(wB), "+v"(wD));
      uint4 ww = {wA, wB, wC, wD};
      pa[ks] = __builtin_bit_cast(bf16x8, ww);
    }
    // PV(t) from VL[(t+1)&1]
    __builtin_amdgcn_s_setprio(1);
#pragma unroll
    for (int ks = 0; ks < 4; ++ks)
#pragma unroll
      for (int nb = 0; nb < 4; ++nb) {
        int row = nb * 32 + l31;
        int slot = (2 * ks + hh) ^ (row & 7);
        bf16x8 bv = ld16(&VLp((t + 1) & 1)[row * 64 + slot * 8]);
        o[nb] = MFMA32(pa[ks], bv, o[nb]);
      }
    __builtin_amdgcn_s_setprio(0);
    if (t < 6) {
      asm volatile("s_waitcnt vmcnt(2)" ::: "memory");
      __builtin_amdgcn_s_barrier();
    } else if (t == 6) {
      asm volatile("s_waitcnt vmcnt(0)" ::: "memory");
      __builtin_amdgcn_s_barrier();
    }
  }
#undef STAGE_K
#undef STAGE_V
#undef KLp
#undef VLp
#undef WQB

  float inv = 1.f / l;
#pragma unroll
  for (int r = 0; r < 16; ++r) {
    int qr = (r & 3) + 8 * (r >> 2) + 4 * hh;
    float iv = __shfl(inv, (ln & 32) | qr, 64);
    int row = q0 + qr;
    u16* dst = O + ((size_t)n * 512 + row) * 2048 + h * 128;
    dst[0 * 32 + l31] = f2bf(o[0][r] * iv);
    dst[1 * 32 + l31] = f2bf(o[1][r] * iv);
    dst[2 * 32 + l31] = f2bf(o[2][r] * iv);
    dst[3 * 32 + l31] = f2bf(o[3][r] * iv);
  }
}

// ---------------- FC GEMM (R9/R13 structure, MFMA16, known-good) ----------
__global__ __launch_bounds__(512, 1) void fc_kernel(
    const u16* __restrict__ A, const u16* __restrict__ Bw,
    const float* __restrict__ bias, float* __restrict__ doutF,
    u16* __restrict__ doutB, int last, int bsh) {
  __shared__ u16 AL[3][256 * 64];
  __shared__ u16 BL[3][128 * 64];
  int blk = blockIdx.x;
  int xcd = blk & 7, j = blk >> 3;
  int bn = xcd * 2 + (j & 1), bm = j >> 1;
  int tid = threadIdx.x, wv = tid >> 6, ln = tid & 63;
  int lr = ln & 15, lg = ln >> 4;
  int R0 = bm * 256, C0 = bn * 128;
  int wr = (wv >> 1) * 64, wc = (wv & 1) * 64;
  const u16* gA[4];
  int sA[4];
  const u16* gB[2];
  int sB[2];
#pragma unroll
  for (int i = 0; i < 4; ++i) {
    int r = wv * 32 + i * 8 + (ln >> 3);
    int cs = ((ln & 7) ^ (r & 7)) * 8;
    gA[i] = A + (size_t)(R0 + r) * 2048 + cs;
    sA[i] = (wv * 32 + i * 8) * 64;
  }
#pragma unroll
  for (int i = 0; i < 2; ++i) {
    int r = wv * 16 + i * 8 + (ln >> 3);
    int cs = ((ln & 7) ^ (r & 7)) * 8;
    gB[i] = Bw + (size_t)(C0 + r) * 2048 + cs;
    sB[i] = (wv * 16 + i * 8) * 64;
  }
  int aoff[4][2], boff[4][2];
#pragma unroll
  for (int i = 0; i < 4; ++i) {
    int ra = wr + i * 16 + lr, rb = wc + i * 16 + lr;
#pragma unroll
    for (int kk = 0; kk < 2; ++kk) {
      aoff[i][kk] = ra * 64 + (((kk * 4 + lg) ^ (ra & 7)) * 8);
      boff[i][kk] = rb * 64 + (((kk * 4 + lg) ^ (rb & 7)) * 8);
    }
  }
  f32x4 acc[4][4] = {};

#define STAGE6(buf, k0)                          \
  {                                              \
    gl_lds(gA[0] + (k0), &AL[buf][sA[0]]);       \
    gl_lds(gA[1] + (k0), &AL[buf][sA[1]]);       \
    gl_lds(gA[2] + (k0), &AL[buf][sA[2]]);       \
    gl_lds(gA[3] + (k0), &AL[buf][sA[3]]);       \
    gl_lds(gB[0] + (k0), &BL[buf][sB[0]]);       \
    gl_lds(gB[1] + (k0), &BL[buf][sB[1]]);       \
  }

  STAGE6(0, 0);
  STAGE6(1, 64);
  asm volatile("s_waitcnt vmcnt(6)" ::: "memory");
  __builtin_amdgcn_s_barrier();

  for (int t = 0; t < 32; ++t) {
    int cur = t % 3, nx2 = (t + 2) % 3;
    int k2 = (t + 2) * 64;
    bf16x8 a0 = ld16(&AL[cur][aoff[0][0]]), a1 = ld16(&AL[cur][aoff[1][0]]);
    bf16x8 a2 = ld16(&AL[cur][aoff[2][0]]), a3 = ld16(&AL[cur][aoff[3][0]]);
    bf16x8 b0 = ld16(&BL[cur][boff[0][0]]), b1 = ld16(&BL[cur][boff[1][0]]);
    bf16x8 b2 = ld16(&BL[cur][boff[2][0]]), b3 = ld16(&BL[cur][boff[3][0]]);
    if (t < 30) {
      gl_lds(gA[0] + k2, &AL[nx2][sA[0]]);
      gl_lds(gA[1] + k2, &AL[nx2][sA[1]]);
      gl_lds(gB[0] + k2, &BL[nx2][sB[0]]);
    }
    __builtin_amdgcn_s_barrier();
    asm volatile("s_waitcnt lgkmcnt(0)" ::: "memory");
    __builtin_amdgcn_sched_barrier(0);
    __builtin_amdgcn_s_setprio(1);
    acc[0][0] = MFMA16(a0, b0, acc[0][0]);
    acc[0][1] = MFMA16(a0, b1, acc[0][1]);
    acc[0][2] = MFMA16(a0, b2, acc[0][2]);
    acc[0][3] = MFMA16(a0, b3, acc[0][3]);
    acc[1][0] = MFMA16(a1, b0, acc[1][0]);
    acc[1][1] = MFMA16(a1, b1, acc[1][1]);
    acc[1][2] = MFMA16(a1, b2, acc[1][2]);
    acc[1][3] = MFMA16(a1, b3, acc[1][3]);
    acc[2][0] = MFMA16(a2, b0, acc[2][0]);
    acc[2][1] = MFMA16(a2, b1, acc[2][1]);
    acc[2][2] = MFMA16(a2, b2, acc[2][2]);
    acc[2][3] = MFMA16(a2, b3, acc[2][3]);
    acc[3][0] = MFMA16(a3, b0, acc[3][0]);
    acc[3][1] = MFMA16(a3, b1, acc[3][1]);
    acc[3][2] = MFMA16(a3, b2, acc[3][2]);
    acc[3][3] = MFMA16(a3, b3, acc[3][3]);
    __builtin_amdgcn_s_setprio(0);
    __builtin_amdgcn_s_barrier();
    a0 = ld16(&AL[cur][aoff[0][1]]); a1 = ld16(&AL[cur][aoff[1][1]]);
    a2 = ld16(&AL[cur][aoff[2][1]]); a3 = ld16(&AL[cur][aoff[3][1]]);
    b0 = ld16(&BL[cur][boff[0][1]]); b1 = ld16(&BL[cur][boff[1][1]]);
    b2 = ld16(&BL[cur][boff[2][1]]); b3 = ld16(&BL[cur][boff[3][1]]);
    if (t < 30) {
      gl_lds(gA[2] + k2, &AL[nx2][sA[2]]);
      gl_lds(gA[3] + k2, &AL[nx2][sA[3]]);
      gl_lds(gB[1] + k2, &BL[nx2][sB[1]]);
      asm volatile("s_waitcnt vmcnt(6)" ::: "memory");
    } else if (t == 30) {
      asm volatile("s_waitcnt vmcnt(0)" ::: "memory");
    }
    __builtin_amdgcn_s_barrier();
    asm volatile("s_waitcnt lgkmcnt(0)" ::: "memory");
    __builtin_amdgcn_sched_barrier(0);
    __builtin_amdgcn_s_setprio(1);
    acc[0][0] = MFMA16(a0, b0, acc[0][0]);
    acc[0][1] = MFMA16(a0, b1, acc[0][1]);
    acc[0][2] = MFMA16(a0, b2, acc[0][2]);
    acc[0][3] = MFMA16(a0, b3, acc[0][3]);
    acc[1][0] = MFMA16(a1, b0, acc[1][0]);
    acc[1][1] = MFMA16(a1, b1, acc[1][1]);
    acc[1][2] = MFMA16(a1, b2, acc[1][2]);
    acc[1][3] = MFMA16(a1, b3, acc[1][3]);
    acc[2][0] = MFMA16(a2, b0, acc[2][0]);
    acc[2][1] = MFMA16(a2, b1, acc[2][1]);
    acc[2][2] = MFMA16(a2, b2, acc[2][2]);
    acc[2][3] = MFMA16(a2, b3, acc[2][3]);
    acc[3][0] = MFMA16(a3, b0, acc[3][0]);
    acc[3][1] = MFMA16(a3, b1, acc[3][1]);
    acc[3][2] = MFMA16(a3, b2, acc[3][2]);
    acc[3][3] = MFMA16(a3, b3, acc[3][3]);
    __builtin_amdgcn_s_setprio(0);
    __builtin_amdgcn_s_barrier();
  }
#undef STAGE6
#pragma unroll
  for (int nc = 0; nc < 4; ++nc) {
    int e = C0 + wc + nc * 16 + lr;
    float bv = bias[e];
    int i = e >> 8, cc = e & 255;
#pragma unroll
    for (int mt = 0; mt < 4; ++mt)
#pragma unroll
      for (int r = 0; r < 4; ++r) {
        int row = R0 + wr + mt * 16 + lg * 4 + r;
        int nn = row >> 9, jj = row & 511;
        int pos = (8 * jj + i - bsh) & 4095;
        size_t di = ((size_t)nn * 4096 + pos) * 256 + cc;
        float v = acc[mt][nc][r] + bv;
        if (last) doutF[di] = v;
        else doutB[di] = f2bf(v);
      }
  }
}

extern "C" void kernel_launch(void* const* d_in, const int* in_sizes, int n_in,
                              void* d_out, int out_size, void* d_ws, size_t ws_size,
                              hipStream_t stream) {
  const float* M = (const float*)d_in[0];
  const float* Wq = (const float*)d_in[1];
  const float* Wk = (const float*)d_in[2];
  const float* Wv = (const float*)d_in[3];
  const float* fcw = (const float*)d_in[4];
  const float* fcb = (const float*)d_in[5];
  float* out = (float*)d_out;
  char* ws = (char*)d_ws;
  u16* wq_b = (u16*)(ws + (0 << 10));
  u16* wk_b = (u16*)(ws + (32 << 10));
  u16* wv_b = (u16*)(ws + (64 << 10));
  u16* fcw_b = (u16*)(ws + (128 << 10));
  u16* Kb = (u16*)(ws + ((size_t)32 << 20));
  u16* Vtb = (u16*)(ws + ((size_t)48 << 20));
  u16* Ab = (u16*)(ws + ((size_t)64 << 20));
  u16* Sb = (u16*)(ws + ((size_t)96 << 20));  // bf16 state (16.8 MB)

  convert_weights<<<8208, 256, 0, stream>>>(Wq, Wk, Wv, fcw, M, wq_b, wk_b,
                                            wv_b, fcw_b, Sb);
  for (int b = 0; b < 8; ++b) {
    kv_kernel<<<dim3(8, 8, 8), 512, 0, stream>>>(Sb, wk_b, wv_b, Kb, Vtb, b);
    attn_kernel<<<256, 512, 0, stream>>>(Sb, wq_b, Kb, Vtb, Ab, b);
    fc_kernel<<<256, 512, 0, stream>>>(Ab, fcw_b, fcb, out, Sb,
                                       (b == 7) ? 1 : 0, b);
  }
}